// Round 11
// baseline (1089.200 us; speedup 1.0000x reference)
//
#include <hip/hip_runtime.h>
#include <stdint.h>

// Persistent-kernel LSTM NAS controller rollout — tagged dataflow + candidate
// speculation + REDUNDANT hw2 (hop B eliminated).
// r5-r10: cross-WG RT ~4.4us is mechanism-invariant; r10 cut 3 RTs -> 2 by
// speculating cell2 over all candidate node indices. This round removes the
// hw2 exchange: every WG computes the FULL hw2 = W2.h1 vector redundantly
// from its staged s_h1, streaming W2 (1 MB) from per-XCD L2 (~8 MB/step/XCD
// at ~4.3 TB/s = ~1.9us < 4.4us RT). Reduction order = r10's exact
// (lane-over-64k+lane dot8 + wredsum per row) -> bit-identical hw2 in every
// WG -> identical ni everywhere. 1 RT/step (h1) + warm cand read remain.
// 64 wgs x 512 thr; one unit per wave; weights register-stationary.
// Tags: A=3t+2 (h1, aw1 row t), K=3t+4 (candidates); init h0 tag 1.
// RNG: JAX threefry2x32 partitionable (bit-exact rounds 2-10).

#define KWG    64
#define NTH    512
#define LSTEPS 32
#define DDIM   512
#define NOPS   16
#define NEGC   (-1.0e9f)

// ---------------- threefry2x32 core ----------------
static __device__ __forceinline__ void tf2x32(uint32_t k0, uint32_t k1,
                                              uint32_t c0, uint32_t c1,
                                              uint32_t& o0, uint32_t& o1){
  uint32_t ks2 = k0 ^ k1 ^ 0x1BD11BDAu;
  uint32_t x0 = c0 + k0;
  uint32_t x1 = c1 + k1;
#define TFR(r) { x0 += x1; x1 = (x1 << (r)) | (x1 >> (32 - (r))); x1 ^= x0; }
  TFR(13) TFR(15) TFR(26) TFR(6)
  x0 += k1;  x1 += ks2 + 1u;
  TFR(17) TFR(29) TFR(16) TFR(24)
  x0 += ks2; x1 += k0 + 2u;
  TFR(13) TFR(15) TFR(26) TFR(6)
  x0 += k0;  x1 += k1 + 3u;
  TFR(17) TFR(29) TFR(16) TFR(24)
  x0 += k1;  x1 += ks2 + 4u;
  TFR(13) TFR(15) TFR(26) TFR(6)
  x0 += ks2; x1 += k0 + 5u;
#undef TFR
  o0 = x0; o1 = x1;
}

static __device__ __forceinline__ float gumbel_bits(uint32_t bits){
  float f = __uint_as_float((bits >> 9) | 0x3f800000u) - 1.0f;
  float u = (f == 0.0f) ? 1.1754943508222875e-38f : f;
  return -logf(-logf(u));
}

static __device__ __forceinline__ float sigm(float x){
  return 1.0f / (1.0f + expf(-x));
}

static __device__ __forceinline__ float wredsum(float v){
  #pragma unroll
  for (int m = 32; m; m >>= 1) v += __shfl_xor(v, m, 64);
  return v;
}

// gather 8 elems at stride 64: d = 64k + lane  (global or LDS)
static __device__ __forceinline__ void gl8(const float* __restrict__ p, int lane, float* r){
  #pragma unroll
  for (int k = 0; k < 8; ++k) r[k] = p[(k << 6) + lane];
}

static __device__ __forceinline__ float dot8(const float* w, const float* x){
  float s = 0.f;
  #pragma unroll
  for (int k = 0; k < 8; ++k) s += w[k]*x[k];
  return s;
}

// ---------------- tagged-atomic helpers (relaxed agent, at MALL) ----------
static __device__ __forceinline__ uint64_t tpack(uint32_t tag, float f){
  return ((uint64_t)tag << 32) | (uint64_t)__float_as_uint(f);
}
static __device__ __forceinline__ uint64_t ald64(const uint64_t* p){
  return __hip_atomic_load(p, __ATOMIC_RELAXED, __HIP_MEMORY_SCOPE_AGENT);
}
static __device__ __forceinline__ void ast64(uint64_t* p, uint64_t v){
  __hip_atomic_store(p, v, __ATOMIC_RELAXED, __HIP_MEMORY_SCOPE_AGENT);
}
static __device__ __forceinline__ float poll1(const uint64_t* p, uint32_t tag){
  uint64_t v = ald64(p);
  while ((uint32_t)(v >> 32) != tag){
    __builtin_amdgcn_s_sleep(1);
    v = ald64(p);
  }
  return __uint_as_float((uint32_t)v);
}
// poll 8 cells (d=64k+lane) into registers (aw1 register rows)
static __device__ __forceinline__ void poll8s(const uint64_t* base, int lane,
                                              uint32_t tag, float* r){
  uint64_t v[8];
  for (;;){
    #pragma unroll
    for (int k = 0; k < 8; ++k) v[k] = ald64(base + (k << 6) + lane);
    bool ok = true;
    #pragma unroll
    for (int k = 0; k < 8; ++k) ok &= ((uint32_t)(v[k] >> 32) == tag);
    if (ok) break;
    __builtin_amdgcn_s_sleep(1);
  }
  #pragma unroll
  for (int k = 0; k < 8; ++k) r[k] = __uint_as_float((uint32_t)v[k]);
}

__global__ void __launch_bounds__(NTH, 2)
Controller_60601988547087_kernel(const float* __restrict__ emb,
                                 const float* __restrict__ wih,
                                 const float* __restrict__ whh,
                                 const float* __restrict__ bih,
                                 const float* __restrict__ bhh,
                                 const float* __restrict__ wa1,
                                 const float* __restrict__ wa2,
                                 const float* __restrict__ idxfc,
                                 const float* __restrict__ opfc,
                                 float* __restrict__ out,
                                 uint64_t* __restrict__ ws64)
{
  const int tid  = threadIdx.x;
  const int wg   = blockIdx.x;
  const int wave = tid >> 6;              // 0..7
  const int lane = tid & 63;
  const int unit = (wg << 3) | wave;      // one hidden unit per wave, 512 total

  // workspace (u64 tagged cells)
  uint64_t* bufA64 = ws64;                // h1      [512]      tags 3t+2
  uint64_t* bufB64 = ws64 + 512;          // h0 init [512]      tag 1
  uint64_t* aw1g64 = ws64 + 1536;         // aw1 rows[32][512], row t tag 3t+2
  uint64_t* cand64 = ws64 + 1536 + 32*512;// h2 candidates [33][512], tags 3t+4

  __shared__ float s_hc[DDIM];            // carry h (selected h2) staging
  __shared__ float s_h1[DDIM];            // h after cell1
  __shared__ float s_hw2[DDIM];           // h1 @ w_attn_2^T (computed locally)
  __shared__ float s_xproj[17 * 32];      // [op][wave][gate] static W_ih·emb[op]
  __shared__ float s_aproj[33 * 33];      // [row][wave*4+g] stride 33 (bank-safe)
  __shared__ float s_opfc[NOPS * DDIM];   // 32 KB op_fc
  __shared__ float s_logits[33];
  __shared__ float s_oplog[16];
  __shared__ int   s_ibc[2];

  // ---- weights register-stationary, gathered at d = 64k+lane ----
  float wihr[4][8], whhr[4][8], a1r[8], fcr[8], bsum[4];
  #pragma unroll
  for (int g = 0; g < 4; ++g){
    gl8(wih + (size_t)((g << 9) + unit) * DDIM, lane, wihr[g]);
    gl8(whh + (size_t)((g << 9) + unit) * DDIM, lane, whhr[g]);
    bsum[g] = bih[(g << 9) + unit] + bhh[(g << 9) + unit];
  }
  gl8(wa1 + (size_t)unit * DDIM, lane, a1r);
  gl8(idxfc, lane, fcr);

  for (int i = tid; i < NOPS * DDIM; i += NTH) s_opfc[i] = opfc[i];
  if (tid < 33) s_aproj[tid] = 0.0f;      // aproj row 0: anchors[0] = zeros

  // ---- static x-projections: s_xproj[op][wave][g] = (W_ih · emb[op])[unit] ----
  for (int op = 0; op <= NOPS; ++op){
    float xc[8];
    gl8(emb + (size_t)op * DDIM, lane, xc);
    #pragma unroll
    for (int g = 0; g < 4; ++g){
      float xp = wredsum(dot8(wihr[g], xc));
      if (lane == 0) s_xproj[op * 32 + (wave << 2) + g] = xp;
    }
  }
  __syncthreads();

  // per-wave register cache of aw1 rows (row r owned by wave r&7, slot r>>3)
  float row0[8], row1[8], row2[8], row3[8];

  // ---- init: h0 = cell(emb[16],0,0) via xproj; publish bufB tag 1 ----
  float cst;
  {
    const float* xp = s_xproj + 16 * 32 + (wave << 2);
    float gi = sigm(xp[0] + bsum[0]);
    float go = sigm(xp[3] + bsum[3]);
    cst = gi * tanhf(xp[2] + bsum[2]);   // c=0: forget term vanishes exactly
    float h0 = go * tanhf(cst);
    if (lane == 0) ast64(bufB64 + unit, tpack(1u, h0));
  }
  s_hc[tid] = poll1(bufB64 + tid, 1u);   // stage carry h (= h0)
  __syncthreads();

  uint32_t key0 = 0u, key1v = 42u;       // jax.random.key(42) -> (0, 42)
  float ent_sum = 0.f, lp_sum = 0.f;
  int prev_op = NOPS;                    // inp0 = embedding[16]

  for (int t = 0; t < LSTEPS; ++t){
    const uint32_t tagA = 3u*(uint32_t)t + 2u;
    const uint32_t tagK = 3u*(uint32_t)t + 4u;   // candidates

    float hc8[8];
    gl8(s_hc, lane, hc8);                // h2^(t-1) (= anchors[t] for t>=1; h0 at t=0)

    // ========== Stage A (critical): cell1 = xproj[prev_op] + W_hh·h ==========
    {
      const float* xp = s_xproj + prev_op * 32 + (wave << 2);
      float p0 = wredsum(dot8(whhr[0], hc8));
      float p1 = wredsum(dot8(whhr[1], hc8));
      float p2 = wredsum(dot8(whhr[2], hc8));
      float p3 = wredsum(dot8(whhr[3], hc8));
      float gi = sigm(xp[0] + p0 + bsum[0]);
      float gf = sigm(xp[1] + p1 + bsum[1]);
      float go = sigm(xp[3] + p3 + bsum[3]);
      cst = gf * cst + gi * tanhf(xp[2] + p2 + bsum[2]);
      float hn = go * tanhf(cst);
      if (lane == 0) ast64(bufA64 + unit, tpack(tagA, hn));
    }
    // ---- hop-A shadow: aw1 row t publish, aproj row t, owner row fetch ----
    {
      float pa = wredsum(dot8(a1r, hc8));              // row t = W1·h2^(t-1)
      if (lane == 0) ast64(aw1g64 + (size_t)t * DDIM + unit, tpack(tagA, pa));
      if (t > 0){                                      // aproj[t] = W_ih·anchors[t]
        #pragma unroll
        for (int g = 0; g < 4; ++g){
          float ap = wredsum(dot8(wihr[g], hc8));
          if (lane == 0) s_aproj[t * 33 + (wave << 2) + g] = ap;
        }
      }
    }
    if (wave == (t & 7)){                              // owner caches row t
      const uint64_t* rb = aw1g64 + (size_t)t * DDIM;
      int slot = t >> 3;
      if      (slot == 0) poll8s(rb, lane, tagA, row0);
      else if (slot == 1) poll8s(rb, lane, tagA, row1);
      else if (slot == 2) poll8s(rb, lane, tagA, row2);
      else                poll8s(rb, lane, tagA, row3);
    }
    s_h1[tid] = poll1(bufA64 + tid, tagA);             // hop A (the ONE RT)
    __syncthreads();

    // ========== ghh + candidate cell2 publish (stores drain during hw2) ======
    float h18[8];
    gl8(s_h1, lane, h18);
    float ghh0 = wredsum(dot8(whhr[0], h18));
    float ghh1 = wredsum(dot8(whhr[1], h18));
    float ghh2 = wredsum(dot8(whhr[2], h18));
    float ghh3 = wredsum(dot8(whhr[3], h18));
    float cst_cand = 0.f;
    if (lane <= t){                                    // lane i owns candidate i
      const float* ag = s_aproj + lane * 33 + (wave << 2);
      float gi = sigm(ag[0] + ghh0 + bsum[0]);
      float gf = sigm(ag[1] + ghh1 + bsum[1]);
      float go = sigm(ag[3] + ghh3 + bsum[3]);
      cst_cand = gf * cst + gi * tanhf(ag[2] + ghh2 + bsum[2]);
      float h2c = go * tanhf(cst_cand);
      ast64(cand64 + (size_t)lane * DDIM + unit, tpack(tagK, h2c));
    }

    // ========== REDUNDANT full hw2 = W2·h1, streamed from L2 (no RT) ========
    // Same reduction order as r10 (dot8 over 64k+lane + wredsum) -> hw2 is
    // bit-identical in every WG -> identical ni everywhere.
    for (int j = 0; j < 64; ++j){
      int i = (wave << 6) | j;
      const float* wr = wa2 + (size_t)i * DDIM;
      float acc = 0.f;
      #pragma unroll
      for (int k = 0; k < 8; ++k) acc += wr[(k << 6) + lane] * h18[k];
      acc = wredsum(acc);
      if (lane == 0) s_hw2[i] = acc;
    }
    __syncthreads();

    // ======== Node logits + sampling — EVERY WG, bit-identical ========
    int ni;
    float nlp_s = 0.f, nent_s = 0.f;
    uint32_t k2a_s = 0u, k2b_s = 0u;
    {
      float h2c[8];
      gl8(s_hw2, lane, h2c);
#define ROWDOT(RR, I)                                                          \
      { int i_ = (I);                                                          \
        if (i_ <= t){                                                          \
          float acc = 0.f;                                                     \
          _Pragma("unroll")                                                    \
          for (int k = 0; k < 8; ++k) acc += tanhf(RR[k] + h2c[k]) * fcr[k];   \
          acc = wredsum(acc);                                                  \
          if (lane == 0) s_logits[i_] = 2.5f * tanhf(acc / 5.0f);              \
        } }
      ROWDOT(row0, wave)
      ROWDOT(row1, wave + 8)
      ROWDOT(row2, wave + 16)
      ROWDOT(row3, wave + 24)
#undef ROWDOT
      __syncthreads();
      if (wave == 0){
        // split(key,3), partitionable/foldlike: row i = tf(key, (0, i))
        uint32_t s0 = 0, s1 = 0;
        if (lane < 3) tf2x32(key0, key1v, 0u, (uint32_t)lane, s0, s1);
        uint32_t k1a = __shfl(s0, 0, 64), k1b = __shfl(s1, 0, 64);
        k2a_s = __shfl(s0, 1, 64); k2b_s = __shfl(s1, 1, 64);
        uint32_t nk0 = __shfl(s0, 2, 64), nk1 = __shfl(s1, 2, 64);
        key0 = nk0; key1v = nk1;
        // 33 random bits: bits[i] = x0 ^ x1 of tf(k1, (0, i))
        uint32_t y0 = 0, y1 = 0;
        if (lane < 33) tf2x32(k1a, k1b, 0u, (uint32_t)lane, y0, y1);
        uint32_t bits = y0 ^ y1;
        float gmb   = gumbel_bits(bits);
        float logit = (lane < 33) ? ((lane <= t) ? s_logits[lane] : NEGC) : -3.0e38f;
        float cand  = (lane < 33) ? (logit + gmb) : -3.0e38f;
        float v = cand; int bi = lane;
        #pragma unroll
        for (int m = 32; m; m >>= 1){
          float ov = __shfl_xor(v, m, 64); int ob = __shfl_xor(bi, m, 64);
          if (ov > v || (ov == v && ob < bi)){ v = ov; bi = ob; }
        }
        int ni_ = bi;
        float lm = (lane < 33) ? logit : -3.0e38f;
        #pragma unroll
        for (int m = 32; m; m >>= 1) lm = fmaxf(lm, __shfl_xor(lm, m, 64));
        float ex   = (lane < 33) ? expf(logit - lm) : 0.f;
        float ssum = wredsum(ex);
        float lsm  = logit - lm - logf(ssum);
        nlp_s  = -__shfl(lsm, ni_, 64);
        float entc = (lane <= t) ? (-lsm * expf(lsm)) : 0.f;
        nent_s = wredsum(entc);
        if (lane == 0) s_ibc[0] = ni_;
      }
      __syncthreads();
      ni = s_ibc[0];
    }

    // ========== Select h2 = cand[ni] (published ~3us ago -> warm) ==========
    cst = __shfl(cst_cand, ni, 64);                    // own unit's cst
    s_hc[tid] = poll1(cand64 + (size_t)ni * DDIM + tid, tagK);
    __syncthreads();

    // ========== Tail (local): op logits + sample -> prev_op ==========
    {
      float h28[8];
      gl8(s_hc, lane, h28);
      #pragma unroll
      for (int jj = 0; jj < 2; ++jj){
        int i = wave + (jj << 3);
        float acc = 0.f;
        #pragma unroll
        for (int k = 0; k < 8; ++k) acc += s_opfc[i * DDIM + (k << 6) + lane] * h28[k];
        acc = wredsum(acc);
        if (lane == 0) s_oplog[i] = tanhf(acc / 5.0f);  // (2.5/2.5)=1 scale
      }
      __syncthreads();
    }
    int oi;
    {
      if (wave == 0){
        // 16 random bits: bits[i] = x0 ^ x1 of tf(k2, (0, i))
        uint32_t z0 = 0, z1 = 0;
        if (lane < 16) tf2x32(k2a_s, k2b_s, 0u, (uint32_t)lane, z0, z1);
        uint32_t bits = z0 ^ z1;
        float gmb   = gumbel_bits(bits);
        float logit = (lane < 16) ? s_oplog[lane] : -3.0e38f;
        float cand  = (lane < 16) ? (logit + gmb) : -3.0e38f;
        float v = cand; int bi = lane;
        #pragma unroll
        for (int m = 32; m; m >>= 1){
          float ov = __shfl_xor(v, m, 64); int ob = __shfl_xor(bi, m, 64);
          if (ov > v || (ov == v && ob < bi)){ v = ov; bi = ob; }
        }
        int oi_ = bi;
        float lm = (lane < 16) ? logit : -3.0e38f;
        #pragma unroll
        for (int m = 32; m; m >>= 1) lm = fmaxf(lm, __shfl_xor(lm, m, 64));
        float ex   = (lane < 16) ? expf(logit - lm) : 0.f;
        float ssum = wredsum(ex);
        float olsm = logit - lm - logf(ssum);
        float olp  = -__shfl(olsm, oi_, 64);
        float oent = wredsum((lane < 16) ? (-olsm * expf(olsm)) : 0.f);
        lp_sum  += nlp_s + olp;
        ent_sum += nent_s + oent;
        if (lane == 0){
          s_ibc[1] = oi_;
          if (wg == 0){
            out[2 * t]     = (float)ni;
            out[2 * t + 1] = (float)oi_;
          }
        }
      }
      __syncthreads();
      oi = s_ibc[1];
    }
    prev_op = oi;
  }

  if (wg == 0 && wave == 0 && lane == 0){
    out[64] = ent_sum;
    out[65] = lp_sum;
  }
}

extern "C" void kernel_launch(void* const* d_in, const int* in_sizes, int n_in,
                              void* d_out, int out_size, void* d_ws, size_t ws_size,
                              hipStream_t stream) {
  (void)in_sizes; (void)n_in; (void)out_size; (void)ws_size;
  const float* emb  = (const float*)d_in[0];
  const float* wih  = (const float*)d_in[1];
  const float* whh  = (const float*)d_in[2];
  const float* bih  = (const float*)d_in[3];
  const float* bhh  = (const float*)d_in[4];
  const float* wa1  = (const float*)d_in[5];
  const float* wa2  = (const float*)d_in[6];
  const float* ifc  = (const float*)d_in[7];
  const float* ofc  = (const float*)d_in[8];
  float* out = (float*)d_out;
  uint64_t* ws = (uint64_t*)d_ws;
  hipLaunchKernelGGL(Controller_60601988547087_kernel,
                     dim3(KWG), dim3(NTH), 0, stream,
                     emb, wih, whh, bih, bhh, wa1, wa2, ifc, ofc, out, ws);
}

// Round 12
// 770.966 us; speedup vs baseline: 1.4128x; 1.4128x over previous
//
#include <hip/hip_runtime.h>
#include <stdint.h>

// Persistent-kernel LSTM NAS controller rollout — tagged dataflow + candidate
// speculation + redundant hw2 with EXPLICIT 8-WAY ILP (hop B eliminated).
// r11 post-mortem: redundant hw2 failed at ~790 cyc/row because 64 per-row
// reductions ran serially (L2 load-wait + 6-deep shfl tree, no ILP). This
// version batches 8 rows: 64 loads issued up front (latency overlapped),
// 8 independent dot8s, interleaved 8-way shuffle trees (chains pipeline on
// the DS unit) -> ~2.3us for all 512 rows, beating the 4.4us RT it replaces.
// Per-row reduction order is EXACTLY r10's (dot8 over 64k+lane, tree m=32..1)
// -> hw2 bit-identical to r10 in every WG -> identical ni everywhere.
// Everything else = r10 (418us, best known): 1 RT/step (h1) + warm cand read.
// 64 wgs x 512 thr; one unit per wave; weights register-stationary.
// Tags: A=3t+2 (h1, aw1 row t), K=3t+4 (candidates); init h0 tag 1.
// RNG: JAX threefry2x32 partitionable (bit-exact rounds 2-11).

#define KWG    64
#define NTH    512
#define LSTEPS 32
#define DDIM   512
#define NOPS   16
#define NEGC   (-1.0e9f)

// ---------------- threefry2x32 core ----------------
static __device__ __forceinline__ void tf2x32(uint32_t k0, uint32_t k1,
                                              uint32_t c0, uint32_t c1,
                                              uint32_t& o0, uint32_t& o1){
  uint32_t ks2 = k0 ^ k1 ^ 0x1BD11BDAu;
  uint32_t x0 = c0 + k0;
  uint32_t x1 = c1 + k1;
#define TFR(r) { x0 += x1; x1 = (x1 << (r)) | (x1 >> (32 - (r))); x1 ^= x0; }
  TFR(13) TFR(15) TFR(26) TFR(6)
  x0 += k1;  x1 += ks2 + 1u;
  TFR(17) TFR(29) TFR(16) TFR(24)
  x0 += ks2; x1 += k0 + 2u;
  TFR(13) TFR(15) TFR(26) TFR(6)
  x0 += k0;  x1 += k1 + 3u;
  TFR(17) TFR(29) TFR(16) TFR(24)
  x0 += k1;  x1 += ks2 + 4u;
  TFR(13) TFR(15) TFR(26) TFR(6)
  x0 += ks2; x1 += k0 + 5u;
#undef TFR
  o0 = x0; o1 = x1;
}

static __device__ __forceinline__ float gumbel_bits(uint32_t bits){
  float f = __uint_as_float((bits >> 9) | 0x3f800000u) - 1.0f;
  float u = (f == 0.0f) ? 1.1754943508222875e-38f : f;
  return -logf(-logf(u));
}

static __device__ __forceinline__ float sigm(float x){
  return 1.0f / (1.0f + expf(-x));
}

static __device__ __forceinline__ float wredsum(float v){
  #pragma unroll
  for (int m = 32; m; m >>= 1) v += __shfl_xor(v, m, 64);
  return v;
}

// gather 8 elems at stride 64: d = 64k + lane  (global or LDS)
static __device__ __forceinline__ void gl8(const float* __restrict__ p, int lane, float* r){
  #pragma unroll
  for (int k = 0; k < 8; ++k) r[k] = p[(k << 6) + lane];
}

static __device__ __forceinline__ float dot8(const float* w, const float* x){
  float s = 0.f;
  #pragma unroll
  for (int k = 0; k < 8; ++k) s += w[k]*x[k];
  return s;
}

// ---------------- tagged-atomic helpers (relaxed agent, at MALL) ----------
static __device__ __forceinline__ uint64_t tpack(uint32_t tag, float f){
  return ((uint64_t)tag << 32) | (uint64_t)__float_as_uint(f);
}
static __device__ __forceinline__ uint64_t ald64(const uint64_t* p){
  return __hip_atomic_load(p, __ATOMIC_RELAXED, __HIP_MEMORY_SCOPE_AGENT);
}
static __device__ __forceinline__ void ast64(uint64_t* p, uint64_t v){
  __hip_atomic_store(p, v, __ATOMIC_RELAXED, __HIP_MEMORY_SCOPE_AGENT);
}
static __device__ __forceinline__ float poll1(const uint64_t* p, uint32_t tag){
  uint64_t v = ald64(p);
  while ((uint32_t)(v >> 32) != tag){
    __builtin_amdgcn_s_sleep(1);
    v = ald64(p);
  }
  return __uint_as_float((uint32_t)v);
}
// poll 8 cells (d=64k+lane) into registers (aw1 register rows)
static __device__ __forceinline__ void poll8s(const uint64_t* base, int lane,
                                              uint32_t tag, float* r){
  uint64_t v[8];
  for (;;){
    #pragma unroll
    for (int k = 0; k < 8; ++k) v[k] = ald64(base + (k << 6) + lane);
    bool ok = true;
    #pragma unroll
    for (int k = 0; k < 8; ++k) ok &= ((uint32_t)(v[k] >> 32) == tag);
    if (ok) break;
    __builtin_amdgcn_s_sleep(1);
  }
  #pragma unroll
  for (int k = 0; k < 8; ++k) r[k] = __uint_as_float((uint32_t)v[k]);
}

__global__ void __launch_bounds__(NTH, 2)
Controller_60601988547087_kernel(const float* __restrict__ emb,
                                 const float* __restrict__ wih,
                                 const float* __restrict__ whh,
                                 const float* __restrict__ bih,
                                 const float* __restrict__ bhh,
                                 const float* __restrict__ wa1,
                                 const float* __restrict__ wa2,
                                 const float* __restrict__ idxfc,
                                 const float* __restrict__ opfc,
                                 float* __restrict__ out,
                                 uint64_t* __restrict__ ws64)
{
  const int tid  = threadIdx.x;
  const int wg   = blockIdx.x;
  const int wave = tid >> 6;              // 0..7
  const int lane = tid & 63;
  const int unit = (wg << 3) | wave;      // one hidden unit per wave, 512 total

  // workspace (u64 tagged cells)
  uint64_t* bufA64 = ws64;                // h1      [512]      tags 3t+2
  uint64_t* bufB64 = ws64 + 512;          // h0 init [512]      tag 1
  uint64_t* aw1g64 = ws64 + 1536;         // aw1 rows[32][512], row t tag 3t+2
  uint64_t* cand64 = ws64 + 1536 + 32*512;// h2 candidates [33][512], tags 3t+4

  __shared__ float s_hc[DDIM];            // carry h (selected h2) staging
  __shared__ float s_h1[DDIM];            // h after cell1
  __shared__ float s_hw2[DDIM];           // h1 @ w_attn_2^T (computed locally)
  __shared__ float s_xproj[17 * 32];      // [op][wave][gate] static W_ih·emb[op]
  __shared__ float s_aproj[33 * 33];      // [row][wave*4+g] stride 33 (bank-safe)
  __shared__ float s_opfc[NOPS * DDIM];   // 32 KB op_fc
  __shared__ float s_logits[33];
  __shared__ float s_oplog[16];
  __shared__ int   s_ibc[2];

  // ---- weights register-stationary, gathered at d = 64k+lane ----
  float wihr[4][8], whhr[4][8], a1r[8], fcr[8], bsum[4];
  #pragma unroll
  for (int g = 0; g < 4; ++g){
    gl8(wih + (size_t)((g << 9) + unit) * DDIM, lane, wihr[g]);
    gl8(whh + (size_t)((g << 9) + unit) * DDIM, lane, whhr[g]);
    bsum[g] = bih[(g << 9) + unit] + bhh[(g << 9) + unit];
  }
  gl8(wa1 + (size_t)unit * DDIM, lane, a1r);
  gl8(idxfc, lane, fcr);

  for (int i = tid; i < NOPS * DDIM; i += NTH) s_opfc[i] = opfc[i];
  if (tid < 33) s_aproj[tid] = 0.0f;      // aproj row 0: anchors[0] = zeros

  // ---- static x-projections: s_xproj[op][wave][g] = (W_ih · emb[op])[unit] ----
  for (int op = 0; op <= NOPS; ++op){
    float xc[8];
    gl8(emb + (size_t)op * DDIM, lane, xc);
    #pragma unroll
    for (int g = 0; g < 4; ++g){
      float xp = wredsum(dot8(wihr[g], xc));
      if (lane == 0) s_xproj[op * 32 + (wave << 2) + g] = xp;
    }
  }
  __syncthreads();

  // per-wave register cache of aw1 rows (row r owned by wave r&7, slot r>>3)
  float row0[8], row1[8], row2[8], row3[8];

  // ---- init: h0 = cell(emb[16],0,0) via xproj; publish bufB tag 1 ----
  float cst;
  {
    const float* xp = s_xproj + 16 * 32 + (wave << 2);
    float gi = sigm(xp[0] + bsum[0]);
    float go = sigm(xp[3] + bsum[3]);
    cst = gi * tanhf(xp[2] + bsum[2]);   // c=0: forget term vanishes exactly
    float h0 = go * tanhf(cst);
    if (lane == 0) ast64(bufB64 + unit, tpack(1u, h0));
  }
  s_hc[tid] = poll1(bufB64 + tid, 1u);   // stage carry h (= h0)
  __syncthreads();

  uint32_t key0 = 0u, key1v = 42u;       // jax.random.key(42) -> (0, 42)
  float ent_sum = 0.f, lp_sum = 0.f;
  int prev_op = NOPS;                    // inp0 = embedding[16]

  for (int t = 0; t < LSTEPS; ++t){
    const uint32_t tagA = 3u*(uint32_t)t + 2u;
    const uint32_t tagK = 3u*(uint32_t)t + 4u;   // candidates

    float hc8[8];
    gl8(s_hc, lane, hc8);                // h2^(t-1) (= anchors[t] for t>=1; h0 at t=0)

    // ========== Stage A (critical): cell1 = xproj[prev_op] + W_hh·h ==========
    {
      const float* xp = s_xproj + prev_op * 32 + (wave << 2);
      float p0 = wredsum(dot8(whhr[0], hc8));
      float p1 = wredsum(dot8(whhr[1], hc8));
      float p2 = wredsum(dot8(whhr[2], hc8));
      float p3 = wredsum(dot8(whhr[3], hc8));
      float gi = sigm(xp[0] + p0 + bsum[0]);
      float gf = sigm(xp[1] + p1 + bsum[1]);
      float go = sigm(xp[3] + p3 + bsum[3]);
      cst = gf * cst + gi * tanhf(xp[2] + p2 + bsum[2]);
      float hn = go * tanhf(cst);
      if (lane == 0) ast64(bufA64 + unit, tpack(tagA, hn));
    }
    // ---- hop-A shadow: aw1 row t publish, aproj row t, owner row fetch ----
    {
      float pa = wredsum(dot8(a1r, hc8));              // row t = W1·h2^(t-1)
      if (lane == 0) ast64(aw1g64 + (size_t)t * DDIM + unit, tpack(tagA, pa));
      if (t > 0){                                      // aproj[t] = W_ih·anchors[t]
        #pragma unroll
        for (int g = 0; g < 4; ++g){
          float ap = wredsum(dot8(wihr[g], hc8));
          if (lane == 0) s_aproj[t * 33 + (wave << 2) + g] = ap;
        }
      }
    }
    if (wave == (t & 7)){                              // owner caches row t
      const uint64_t* rb = aw1g64 + (size_t)t * DDIM;
      int slot = t >> 3;
      if      (slot == 0) poll8s(rb, lane, tagA, row0);
      else if (slot == 1) poll8s(rb, lane, tagA, row1);
      else if (slot == 2) poll8s(rb, lane, tagA, row2);
      else                poll8s(rb, lane, tagA, row3);
    }
    s_h1[tid] = poll1(bufA64 + tid, tagA);             // hop A (the ONE RT)
    __syncthreads();

    // ========== ghh + candidate cell2 publish (stores drain during hw2) ======
    float h18[8];
    gl8(s_h1, lane, h18);
    float ghh0 = wredsum(dot8(whhr[0], h18));
    float ghh1 = wredsum(dot8(whhr[1], h18));
    float ghh2 = wredsum(dot8(whhr[2], h18));
    float ghh3 = wredsum(dot8(whhr[3], h18));
    float cst_cand = 0.f;
    if (lane <= t){                                    // lane i owns candidate i
      const float* ag = s_aproj + lane * 33 + (wave << 2);
      float gi = sigm(ag[0] + ghh0 + bsum[0]);
      float gf = sigm(ag[1] + ghh1 + bsum[1]);
      float go = sigm(ag[3] + ghh3 + bsum[3]);
      cst_cand = gf * cst + gi * tanhf(ag[2] + ghh2 + bsum[2]);
      float h2c = go * tanhf(cst_cand);
      ast64(cand64 + (size_t)lane * DDIM + unit, tpack(tagK, h2c));
    }

    // ====== REDUNDANT hw2 = W2·h1, 8-row ILP blocks (no RT, no r11 trap) =====
    // Exact r10 per-row order: dot8 over 64k+lane, tree m=32..1. 8 rows per
    // block: 64 loads batched (latency overlapped), 8 independent dot8s,
    // interleaved shuffle trees (chains pipeline on the DS unit).
    for (int jb = 0; jb < 8; ++jb){
      const int ibase = (wave << 6) | (jb << 3);
      float wr[8][8];
      #pragma unroll
      for (int r = 0; r < 8; ++r)
        gl8(wa2 + (size_t)(ibase + r) * DDIM, lane, wr[r]);
      float a[8];
      #pragma unroll
      for (int r = 0; r < 8; ++r) a[r] = dot8(wr[r], h18);
      #pragma unroll
      for (int m = 32; m; m >>= 1){
        #pragma unroll
        for (int r = 0; r < 8; ++r) a[r] += __shfl_xor(a[r], m, 64);
      }
      if (lane == 0){
        #pragma unroll
        for (int r = 0; r < 8; ++r) s_hw2[ibase + r] = a[r];
      }
    }
    __syncthreads();

    // ======== Node logits + sampling — EVERY WG, bit-identical ========
    int ni;
    float nlp_s = 0.f, nent_s = 0.f;
    uint32_t k2a_s = 0u, k2b_s = 0u;
    {
      float h2c[8];
      gl8(s_hw2, lane, h2c);
#define ROWDOT(RR, I)                                                          \
      { int i_ = (I);                                                          \
        if (i_ <= t){                                                          \
          float acc = 0.f;                                                     \
          _Pragma("unroll")                                                    \
          for (int k = 0; k < 8; ++k) acc += tanhf(RR[k] + h2c[k]) * fcr[k];   \
          acc = wredsum(acc);                                                  \
          if (lane == 0) s_logits[i_] = 2.5f * tanhf(acc / 5.0f);              \
        } }
      ROWDOT(row0, wave)
      ROWDOT(row1, wave + 8)
      ROWDOT(row2, wave + 16)
      ROWDOT(row3, wave + 24)
#undef ROWDOT
      __syncthreads();
      if (wave == 0){
        // split(key,3), partitionable/foldlike: row i = tf(key, (0, i))
        uint32_t s0 = 0, s1 = 0;
        if (lane < 3) tf2x32(key0, key1v, 0u, (uint32_t)lane, s0, s1);
        uint32_t k1a = __shfl(s0, 0, 64), k1b = __shfl(s1, 0, 64);
        k2a_s = __shfl(s0, 1, 64); k2b_s = __shfl(s1, 1, 64);
        uint32_t nk0 = __shfl(s0, 2, 64), nk1 = __shfl(s1, 2, 64);
        key0 = nk0; key1v = nk1;
        // 33 random bits: bits[i] = x0 ^ x1 of tf(k1, (0, i))
        uint32_t y0 = 0, y1 = 0;
        if (lane < 33) tf2x32(k1a, k1b, 0u, (uint32_t)lane, y0, y1);
        uint32_t bits = y0 ^ y1;
        float gmb   = gumbel_bits(bits);
        float logit = (lane < 33) ? ((lane <= t) ? s_logits[lane] : NEGC) : -3.0e38f;
        float cand  = (lane < 33) ? (logit + gmb) : -3.0e38f;
        float v = cand; int bi = lane;
        #pragma unroll
        for (int m = 32; m; m >>= 1){
          float ov = __shfl_xor(v, m, 64); int ob = __shfl_xor(bi, m, 64);
          if (ov > v || (ov == v && ob < bi)){ v = ov; bi = ob; }
        }
        int ni_ = bi;
        float lm = (lane < 33) ? logit : -3.0e38f;
        #pragma unroll
        for (int m = 32; m; m >>= 1) lm = fmaxf(lm, __shfl_xor(lm, m, 64));
        float ex   = (lane < 33) ? expf(logit - lm) : 0.f;
        float ssum = wredsum(ex);
        float lsm  = logit - lm - logf(ssum);
        nlp_s  = -__shfl(lsm, ni_, 64);
        float entc = (lane <= t) ? (-lsm * expf(lsm)) : 0.f;
        nent_s = wredsum(entc);
        if (lane == 0) s_ibc[0] = ni_;
      }
      __syncthreads();
      ni = s_ibc[0];
    }

    // ========== Select h2 = cand[ni] (published ~3us ago -> warm) ==========
    cst = __shfl(cst_cand, ni, 64);                    // own unit's cst
    s_hc[tid] = poll1(cand64 + (size_t)ni * DDIM + tid, tagK);
    __syncthreads();

    // ========== Tail (local): op logits + sample -> prev_op ==========
    {
      float h28[8];
      gl8(s_hc, lane, h28);
      #pragma unroll
      for (int jj = 0; jj < 2; ++jj){
        int i = wave + (jj << 3);
        float acc = 0.f;
        #pragma unroll
        for (int k = 0; k < 8; ++k) acc += s_opfc[i * DDIM + (k << 6) + lane] * h28[k];
        acc = wredsum(acc);
        if (lane == 0) s_oplog[i] = tanhf(acc / 5.0f);  // (2.5/2.5)=1 scale
      }
      __syncthreads();
    }
    int oi;
    {
      if (wave == 0){
        // 16 random bits: bits[i] = x0 ^ x1 of tf(k2, (0, i))
        uint32_t z0 = 0, z1 = 0;
        if (lane < 16) tf2x32(k2a_s, k2b_s, 0u, (uint32_t)lane, z0, z1);
        uint32_t bits = z0 ^ z1;
        float gmb   = gumbel_bits(bits);
        float logit = (lane < 16) ? s_oplog[lane] : -3.0e38f;
        float cand  = (lane < 16) ? (logit + gmb) : -3.0e38f;
        float v = cand; int bi = lane;
        #pragma unroll
        for (int m = 32; m; m >>= 1){
          float ov = __shfl_xor(v, m, 64); int ob = __shfl_xor(bi, m, 64);
          if (ov > v || (ov == v && ob < bi)){ v = ov; bi = ob; }
        }
        int oi_ = bi;
        float lm = (lane < 16) ? logit : -3.0e38f;
        #pragma unroll
        for (int m = 32; m; m >>= 1) lm = fmaxf(lm, __shfl_xor(lm, m, 64));
        float ex   = (lane < 16) ? expf(logit - lm) : 0.f;
        float ssum = wredsum(ex);
        float olsm = logit - lm - logf(ssum);
        float olp  = -__shfl(olsm, oi_, 64);
        float oent = wredsum((lane < 16) ? (-olsm * expf(olsm)) : 0.f);
        lp_sum  += nlp_s + olp;
        ent_sum += nent_s + oent;
        if (lane == 0){
          s_ibc[1] = oi_;
          if (wg == 0){
            out[2 * t]     = (float)ni;
            out[2 * t + 1] = (float)oi_;
          }
        }
      }
      __syncthreads();
      oi = s_ibc[1];
    }
    prev_op = oi;
  }

  if (wg == 0 && wave == 0 && lane == 0){
    out[64] = ent_sum;
    out[65] = lp_sum;
  }
}

extern "C" void kernel_launch(void* const* d_in, const int* in_sizes, int n_in,
                              void* d_out, int out_size, void* d_ws, size_t ws_size,
                              hipStream_t stream) {
  (void)in_sizes; (void)n_in; (void)out_size; (void)ws_size;
  const float* emb  = (const float*)d_in[0];
  const float* wih  = (const float*)d_in[1];
  const float* whh  = (const float*)d_in[2];
  const float* bih  = (const float*)d_in[3];
  const float* bhh  = (const float*)d_in[4];
  const float* wa1  = (const float*)d_in[5];
  const float* wa2  = (const float*)d_in[6];
  const float* ifc  = (const float*)d_in[7];
  const float* ofc  = (const float*)d_in[8];
  float* out = (float*)d_out;
  uint64_t* ws = (uint64_t*)d_ws;
  hipLaunchKernelGGL(Controller_60601988547087_kernel,
                     dim3(KWG), dim3(NTH), 0, stream,
                     emb, wih, whh, bih, bhh, wa1, wa2, ifc, ofc, out, ws);
}

// Round 13
// 424.255 us; speedup vs baseline: 2.5673x; 1.8172x over previous
//
#include <hip/hip_runtime.h>
#include <stdint.h>

// Persistent-kernel LSTM NAS controller rollout — tagged dataflow + DOUBLE
// speculation: cell2 over node-index (r10) AND cell1 over op-index (new).
// r10 (418us, best): 2 cold RTs/step (h1, hw2). r11/r12: redundant hw2 via
// L2 streaming is 5x slower than modeled — dead end, hw2 stays an exchange.
// New: cell1 h1 = f(xproj[op] + W_hh*h_carry) is speculatable over the 17
// possible prev_op values (xproj is a static table). At the tail of step t-1,
// right after h2 is staged and BEFORE op sampling, each wave computes
// p = W_hh*h2 once + all 17 h1 candidates (lane=op, ~30 ALU each) and
// publishes h1c[op][unit]. After oi is known (bit-identical in every WG),
// step t polls h1c[oi] — published ~1us earlier -> warm read (the same
// publish-early effect that made r10's cand[ni] read cheap).
// cst chains via two shfl selects: c1 = shfl(cst1_cand, oi),
// c2 = shfl(cst2_cand, ni). Overwrite safety: h1c re-publish at tail(t) is
// gated through every WG's hw2(t) publish, which follows its h1c(t) read.
// 64 wgs x 512 thr; one unit per wave; weights register-stationary.
// Tags: H=4t+1 (h1c rows + aw1 row t, published tail(t-1)/preloop),
//       B=4t+2 (hw2), K=4t+3 (cand); h0 exchange tag 1 in cand row 32.
// RNG: JAX threefry2x32 partitionable (bit-exact rounds 2-12).

#define KWG    64
#define NTH    512
#define LSTEPS 32
#define DDIM   512
#define NOPS   16
#define NEGC   (-1.0e9f)

// ---------------- threefry2x32 core ----------------
static __device__ __forceinline__ void tf2x32(uint32_t k0, uint32_t k1,
                                              uint32_t c0, uint32_t c1,
                                              uint32_t& o0, uint32_t& o1){
  uint32_t ks2 = k0 ^ k1 ^ 0x1BD11BDAu;
  uint32_t x0 = c0 + k0;
  uint32_t x1 = c1 + k1;
#define TFR(r) { x0 += x1; x1 = (x1 << (r)) | (x1 >> (32 - (r))); x1 ^= x0; }
  TFR(13) TFR(15) TFR(26) TFR(6)
  x0 += k1;  x1 += ks2 + 1u;
  TFR(17) TFR(29) TFR(16) TFR(24)
  x0 += ks2; x1 += k0 + 2u;
  TFR(13) TFR(15) TFR(26) TFR(6)
  x0 += k0;  x1 += k1 + 3u;
  TFR(17) TFR(29) TFR(16) TFR(24)
  x0 += k1;  x1 += ks2 + 4u;
  TFR(13) TFR(15) TFR(26) TFR(6)
  x0 += ks2; x1 += k0 + 5u;
#undef TFR
  o0 = x0; o1 = x1;
}

static __device__ __forceinline__ float gumbel_bits(uint32_t bits){
  float f = __uint_as_float((bits >> 9) | 0x3f800000u) - 1.0f;
  float u = (f == 0.0f) ? 1.1754943508222875e-38f : f;
  return -logf(-logf(u));
}

static __device__ __forceinline__ float sigm(float x){
  return 1.0f / (1.0f + expf(-x));
}

static __device__ __forceinline__ float wredsum(float v){
  #pragma unroll
  for (int m = 32; m; m >>= 1) v += __shfl_xor(v, m, 64);
  return v;
}

// gather 8 elems at stride 64: d = 64k + lane  (global or LDS)
static __device__ __forceinline__ void gl8(const float* __restrict__ p, int lane, float* r){
  #pragma unroll
  for (int k = 0; k < 8; ++k) r[k] = p[(k << 6) + lane];
}

static __device__ __forceinline__ float dot8(const float* w, const float* x){
  float s = 0.f;
  #pragma unroll
  for (int k = 0; k < 8; ++k) s += w[k]*x[k];
  return s;
}

// ---------------- tagged-atomic helpers (relaxed agent, at MALL) ----------
static __device__ __forceinline__ uint64_t tpack(uint32_t tag, float f){
  return ((uint64_t)tag << 32) | (uint64_t)__float_as_uint(f);
}
static __device__ __forceinline__ uint64_t ald64(const uint64_t* p){
  return __hip_atomic_load(p, __ATOMIC_RELAXED, __HIP_MEMORY_SCOPE_AGENT);
}
static __device__ __forceinline__ void ast64(uint64_t* p, uint64_t v){
  __hip_atomic_store(p, v, __ATOMIC_RELAXED, __HIP_MEMORY_SCOPE_AGENT);
}
static __device__ __forceinline__ float poll1(const uint64_t* p, uint32_t tag){
  uint64_t v = ald64(p);
  while ((uint32_t)(v >> 32) != tag){
    __builtin_amdgcn_s_sleep(1);
    v = ald64(p);
  }
  return __uint_as_float((uint32_t)v);
}
// poll 8 cells (d=64k+lane) into registers (aw1 register rows)
static __device__ __forceinline__ void poll8s(const uint64_t* base, int lane,
                                              uint32_t tag, float* r){
  uint64_t v[8];
  for (;;){
    #pragma unroll
    for (int k = 0; k < 8; ++k) v[k] = ald64(base + (k << 6) + lane);
    bool ok = true;
    #pragma unroll
    for (int k = 0; k < 8; ++k) ok &= ((uint32_t)(v[k] >> 32) == tag);
    if (ok) break;
    __builtin_amdgcn_s_sleep(1);
  }
  #pragma unroll
  for (int k = 0; k < 8; ++k) r[k] = __uint_as_float((uint32_t)v[k]);
}

__global__ void __launch_bounds__(NTH, 2)
Controller_60601988547087_kernel(const float* __restrict__ emb,
                                 const float* __restrict__ wih,
                                 const float* __restrict__ whh,
                                 const float* __restrict__ bih,
                                 const float* __restrict__ bhh,
                                 const float* __restrict__ wa1,
                                 const float* __restrict__ wa2,
                                 const float* __restrict__ idxfc,
                                 const float* __restrict__ opfc,
                                 float* __restrict__ out,
                                 uint64_t* __restrict__ ws64)
{
  const int tid  = threadIdx.x;
  const int wg   = blockIdx.x;
  const int wave = tid >> 6;              // 0..7
  const int lane = tid & 63;
  const int unit = (wg << 3) | wave;      // one hidden unit per wave, 512 total

  // workspace (u64 tagged cells)
  uint64_t* h1c64  = ws64;                  // [17][512] h1 candidates, tag 4t+1
  uint64_t* hw2g64 = ws64 + 17*512;         // [512]     hw2,           tag 4t+2
  uint64_t* aw1g64 = ws64 + 18*512;         // [32][512] aw1 rows, row t tag 4t+1
  uint64_t* cand64 = ws64 + 50*512;         // [33][512] h2 candidates, tag 4t+3
  uint64_t* buf064 = cand64 + 32*512;       // h0 exchange (cand row 32, unused), tag 1

  __shared__ float s_hc[DDIM];            // h2 staging
  __shared__ float s_h1[DDIM];            // h1 staging
  __shared__ float s_hw2[DDIM];           // h1 @ w_attn_2^T
  __shared__ float s_xproj[17 * 32];      // [op][wave*4+g]  W_ih·emb[op]
  __shared__ float s_xprojT[32 * 17];     // [wave*4+g][op]  transposed (lane-indexed path)
  __shared__ float s_aproj[33 * 33];      // [row][wave*4+g] stride 33 (bank-safe)
  __shared__ float s_opfc[NOPS * DDIM];   // 32 KB op_fc
  __shared__ float s_logits[33];
  __shared__ float s_oplog[16];
  __shared__ int   s_ibc[2];

  // ---- weights register-stationary, gathered at d = 64k+lane ----
  float wihr[4][8], whhr[4][8], a1r[8], a2r[8], fcr[8], bsum[4];
  #pragma unroll
  for (int g = 0; g < 4; ++g){
    gl8(wih + (size_t)((g << 9) + unit) * DDIM, lane, wihr[g]);
    gl8(whh + (size_t)((g << 9) + unit) * DDIM, lane, whhr[g]);
    bsum[g] = bih[(g << 9) + unit] + bhh[(g << 9) + unit];
  }
  gl8(wa1 + (size_t)unit * DDIM, lane, a1r);
  gl8(wa2 + (size_t)unit * DDIM, lane, a2r);
  gl8(idxfc, lane, fcr);

  for (int i = tid; i < NOPS * DDIM; i += NTH) s_opfc[i] = opfc[i];
  if (tid < 33) s_aproj[tid] = 0.0f;      // aproj row 0: anchors[0] = zeros

  // ---- static x-projections (both layouts) ----
  for (int op = 0; op <= NOPS; ++op){
    float xc[8];
    gl8(emb + (size_t)op * DDIM, lane, xc);
    #pragma unroll
    for (int g = 0; g < 4; ++g){
      float xp = wredsum(dot8(wihr[g], xc));
      if (lane == 0){
        s_xproj [op * 32 + (wave << 2) + g] = xp;
        s_xprojT[((wave << 2) + g) * 17 + op] = xp;
      }
    }
  }
  __syncthreads();

  // per-wave register cache of aw1 rows (row r owned by wave r&7, slot r>>3)
  float row0[8], row1[8], row2[8], row3[8];

  // ---- init: h0 = cell(emb[16],0,0) via xproj; exchange h0 (tag 1) ----
  float cst;
  {
    const float* xp = s_xproj + 16 * 32 + (wave << 2);
    float gi = sigm(xp[0] + bsum[0]);
    float go = sigm(xp[3] + bsum[3]);
    cst = gi * tanhf(xp[2] + bsum[2]);   // c0 (forget term vanishes, c=0)
    float h0 = go * tanhf(cst);
    if (lane == 0) ast64(buf064 + unit, tpack(1u, h0));
  }
  s_hc[tid] = poll1(buf064 + tid, 1u);   // stage h0
  __syncthreads();

  // ---- pre-loop tail (t=-1): p=W_hh·h0, aw1 row 0, h1c candidates tag 1 ----
  float cst1_cand = 0.f;                 // per-lane (lane=op) cell1 cst candidate
  {
    float hc8[8];
    gl8(s_hc, lane, hc8);
    float p0 = wredsum(dot8(whhr[0], hc8));
    float p1 = wredsum(dot8(whhr[1], hc8));
    float p2 = wredsum(dot8(whhr[2], hc8));
    float p3 = wredsum(dot8(whhr[3], hc8));
    if (lane < 17){                      // lane = op candidate
      const float* xt = s_xprojT;        // [(w4g)*17 + op]
      int w4 = (wave << 2);
      float x0 = xt[(w4+0)*17 + lane], x1 = xt[(w4+1)*17 + lane];
      float x2 = xt[(w4+2)*17 + lane], x3 = xt[(w4+3)*17 + lane];
      float gi = sigm(x0 + p0 + bsum[0]);
      float gf = sigm(x1 + p1 + bsum[1]);
      float go = sigm(x3 + p3 + bsum[3]);
      cst1_cand = gf * cst + gi * tanhf(x2 + p2 + bsum[2]);
      float h1v = go * tanhf(cst1_cand);
      ast64(h1c64 + (size_t)lane * DDIM + unit, tpack(1u, h1v));
    }
    float pa = wredsum(dot8(a1r, hc8));  // aw1 row 0 = W1·h0
    if (lane == 0) ast64(aw1g64 + unit, tpack(1u, pa));
  }

  uint32_t key0 = 0u, key1v = 42u;       // jax.random.key(42) -> (0, 42)
  float ent_sum = 0.f, lp_sum = 0.f;
  int prev_op = NOPS;                    // inp0 = embedding[16]

  for (int t = 0; t < LSTEPS; ++t){
    const uint32_t tagH  = 4u*(uint32_t)t + 1u;  // h1c rows + aw1 row t
    const uint32_t tagB  = 4u*(uint32_t)t + 2u;  // hw2
    const uint32_t tagK  = 4u*(uint32_t)t + 3u;  // cell2 candidates
    const uint32_t tagH2 = 4u*(uint32_t)t + 5u;  // next step's h1c/aw1

    // ---- select cell1 cst for the sampled op; h1 = h1c[prev_op] (warm) ----
    cst = __shfl(cst1_cand, prev_op, 64);        // c1(t)
    if (wave == (t & 7)){                        // owner caches aw1 row t
      const uint64_t* rb = aw1g64 + (size_t)t * DDIM;
      int slot = t >> 3;
      if      (slot == 0) poll8s(rb, lane, tagH, row0);
      else if (slot == 1) poll8s(rb, lane, tagH, row1);
      else if (slot == 2) poll8s(rb, lane, tagH, row2);
      else                poll8s(rb, lane, tagH, row3);
    }
    s_h1[tid] = poll1(h1c64 + (size_t)prev_op * DDIM + tid, tagH);  // warm read
    __syncthreads();

    // ========== hw2 publish; ghh + cell2 candidates in hop-B shadow ==========
    float h18[8];
    gl8(s_h1, lane, h18);
    {
      float q = wredsum(dot8(a2r, h18));
      if (lane == 0) ast64(hw2g64 + unit, tpack(tagB, q));
    }
    float ghh0 = wredsum(dot8(whhr[0], h18));
    float ghh1 = wredsum(dot8(whhr[1], h18));
    float ghh2 = wredsum(dot8(whhr[2], h18));
    float ghh3 = wredsum(dot8(whhr[3], h18));
    float cst2_cand = 0.f;
    if (lane <= t){                              // lane i owns candidate i
      const float* ag = s_aproj + lane * 33 + (wave << 2);
      float gi = sigm(ag[0] + ghh0 + bsum[0]);
      float gf = sigm(ag[1] + ghh1 + bsum[1]);
      float go = sigm(ag[3] + ghh3 + bsum[3]);
      cst2_cand = gf * cst + gi * tanhf(ag[2] + ghh2 + bsum[2]);
      float h2c = go * tanhf(cst2_cand);
      ast64(cand64 + (size_t)lane * DDIM + unit, tpack(tagK, h2c));
    }
    s_hw2[tid] = poll1(hw2g64 + tid, tagB);      // hop B (the one cold RT)
    __syncthreads();

    // ======== Node logits + sampling — EVERY WG, bit-identical ========
    int ni;
    float nlp_s = 0.f, nent_s = 0.f;
    uint32_t k2a_s = 0u, k2b_s = 0u;
    {
      float h2c[8];
      gl8(s_hw2, lane, h2c);
#define ROWDOT(RR, I)                                                          \
      { int i_ = (I);                                                          \
        if (i_ <= t){                                                          \
          float acc = 0.f;                                                     \
          _Pragma("unroll")                                                    \
          for (int k = 0; k < 8; ++k) acc += tanhf(RR[k] + h2c[k]) * fcr[k];   \
          acc = wredsum(acc);                                                  \
          if (lane == 0) s_logits[i_] = 2.5f * tanhf(acc / 5.0f);              \
        } }
      ROWDOT(row0, wave)
      ROWDOT(row1, wave + 8)
      ROWDOT(row2, wave + 16)
      ROWDOT(row3, wave + 24)
#undef ROWDOT
      __syncthreads();
      if (wave == 0){
        // split(key,3), partitionable/foldlike: row i = tf(key, (0, i))
        uint32_t s0 = 0, s1 = 0;
        if (lane < 3) tf2x32(key0, key1v, 0u, (uint32_t)lane, s0, s1);
        uint32_t k1a = __shfl(s0, 0, 64), k1b = __shfl(s1, 0, 64);
        k2a_s = __shfl(s0, 1, 64); k2b_s = __shfl(s1, 1, 64);
        uint32_t nk0 = __shfl(s0, 2, 64), nk1 = __shfl(s1, 2, 64);
        key0 = nk0; key1v = nk1;
        // 33 random bits: bits[i] = x0 ^ x1 of tf(k1, (0, i))
        uint32_t y0 = 0, y1 = 0;
        if (lane < 33) tf2x32(k1a, k1b, 0u, (uint32_t)lane, y0, y1);
        uint32_t bits = y0 ^ y1;
        float gmb   = gumbel_bits(bits);
        float logit = (lane < 33) ? ((lane <= t) ? s_logits[lane] : NEGC) : -3.0e38f;
        float cand  = (lane < 33) ? (logit + gmb) : -3.0e38f;
        float v = cand; int bi = lane;
        #pragma unroll
        for (int m = 32; m; m >>= 1){
          float ov = __shfl_xor(v, m, 64); int ob = __shfl_xor(bi, m, 64);
          if (ov > v || (ov == v && ob < bi)){ v = ov; bi = ob; }
        }
        int ni_ = bi;
        float lm = (lane < 33) ? logit : -3.0e38f;
        #pragma unroll
        for (int m = 32; m; m >>= 1) lm = fmaxf(lm, __shfl_xor(lm, m, 64));
        float ex   = (lane < 33) ? expf(logit - lm) : 0.f;
        float ssum = wredsum(ex);
        float lsm  = logit - lm - logf(ssum);
        nlp_s  = -__shfl(lsm, ni_, 64);
        float entc = (lane <= t) ? (-lsm * expf(lsm)) : 0.f;
        nent_s = wredsum(entc);
        if (lane == 0) s_ibc[0] = ni_;
      }
      __syncthreads();
      ni = s_ibc[0];
    }

    // ========== Select h2 = cand[ni] (published ~1 RT ago -> warm) ==========
    cst = __shfl(cst2_cand, ni, 64);             // c2(t)
    s_hc[tid] = poll1(cand64 + (size_t)ni * DDIM + tid, tagK);
    __syncthreads();

    // ========== Tail: p/W_hh, h1c candidates (publish EARLY), aw1/aproj,
    //            then op logits + sample ==========
    float hc8[8];
    gl8(s_hc, lane, hc8);                        // h2(t)
    if (t < LSTEPS - 1){
      float p0 = wredsum(dot8(whhr[0], hc8));
      float p1 = wredsum(dot8(whhr[1], hc8));
      float p2 = wredsum(dot8(whhr[2], hc8));
      float p3 = wredsum(dot8(whhr[3], hc8));
      if (lane < 17){                            // h1 candidates for step t+1
        const float* xt = s_xprojT;
        int w4 = (wave << 2);
        float x0 = xt[(w4+0)*17 + lane], x1 = xt[(w4+1)*17 + lane];
        float x2 = xt[(w4+2)*17 + lane], x3 = xt[(w4+3)*17 + lane];
        float gi = sigm(x0 + p0 + bsum[0]);
        float gf = sigm(x1 + p1 + bsum[1]);
        float go = sigm(x3 + p3 + bsum[3]);
        cst1_cand = gf * cst + gi * tanhf(x2 + p2 + bsum[2]);
        float h1v = go * tanhf(cst1_cand);
        ast64(h1c64 + (size_t)lane * DDIM + unit, tpack(tagH2, h1v));
      }
      float pa = wredsum(dot8(a1r, hc8));        // aw1 row t+1 = W1·h2(t)
      if (lane == 0) ast64(aw1g64 + (size_t)(t + 1) * DDIM + unit, tpack(tagH2, pa));
      #pragma unroll
      for (int g = 0; g < 4; ++g){               // aproj row t+1 = W_ih·h2(t)
        float ap = wredsum(dot8(wihr[g], hc8));
        if (lane == 0) s_aproj[(t + 1) * 33 + (wave << 2) + g] = ap;
      }
    }
    {
      #pragma unroll
      for (int jj = 0; jj < 2; ++jj){            // op logits
        int i = wave + (jj << 3);
        float acc = 0.f;
        #pragma unroll
        for (int k = 0; k < 8; ++k) acc += s_opfc[i * DDIM + (k << 6) + lane] * hc8[k];
        acc = wredsum(acc);
        if (lane == 0) s_oplog[i] = tanhf(acc / 5.0f);  // (2.5/2.5)=1 scale
      }
      __syncthreads();
    }
    int oi;
    {
      if (wave == 0){
        // 16 random bits: bits[i] = x0 ^ x1 of tf(k2, (0, i))
        uint32_t z0 = 0, z1 = 0;
        if (lane < 16) tf2x32(k2a_s, k2b_s, 0u, (uint32_t)lane, z0, z1);
        uint32_t bits = z0 ^ z1;
        float gmb   = gumbel_bits(bits);
        float logit = (lane < 16) ? s_oplog[lane] : -3.0e38f;
        float cand  = (lane < 16) ? (logit + gmb) : -3.0e38f;
        float v = cand; int bi = lane;
        #pragma unroll
        for (int m = 32; m; m >>= 1){
          float ov = __shfl_xor(v, m, 64); int ob = __shfl_xor(bi, m, 64);
          if (ov > v || (ov == v && ob < bi)){ v = ov; bi = ob; }
        }
        int oi_ = bi;
        float lm = (lane < 16) ? logit : -3.0e38f;
        #pragma unroll
        for (int m = 32; m; m >>= 1) lm = fmaxf(lm, __shfl_xor(lm, m, 64));
        float ex   = (lane < 16) ? expf(logit - lm) : 0.f;
        float ssum = wredsum(ex);
        float olsm = logit - lm - logf(ssum);
        float olp  = -__shfl(olsm, oi_, 64);
        float oent = wredsum((lane < 16) ? (-olsm * expf(olsm)) : 0.f);
        lp_sum  += nlp_s + olp;
        ent_sum += nent_s + oent;
        if (lane == 0){
          s_ibc[1] = oi_;
          if (wg == 0){
            out[2 * t]     = (float)ni;
            out[2 * t + 1] = (float)oi_;
          }
        }
      }
      __syncthreads();
      oi = s_ibc[1];
    }
    prev_op = oi;
  }

  if (wg == 0 && wave == 0 && lane == 0){
    out[64] = ent_sum;
    out[65] = lp_sum;
  }
}

extern "C" void kernel_launch(void* const* d_in, const int* in_sizes, int n_in,
                              void* d_out, int out_size, void* d_ws, size_t ws_size,
                              hipStream_t stream) {
  (void)in_sizes; (void)n_in; (void)out_size; (void)ws_size;
  const float* emb  = (const float*)d_in[0];
  const float* wih  = (const float*)d_in[1];
  const float* whh  = (const float*)d_in[2];
  const float* bih  = (const float*)d_in[3];
  const float* bhh  = (const float*)d_in[4];
  const float* wa1  = (const float*)d_in[5];
  const float* wa2  = (const float*)d_in[6];
  const float* ifc  = (const float*)d_in[7];
  const float* ofc  = (const float*)d_in[8];
  float* out = (float*)d_out;
  uint64_t* ws = (uint64_t*)d_ws;
  hipLaunchKernelGGL(Controller_60601988547087_kernel,
                     dim3(KWG), dim3(NTH), 0, stream,
                     emb, wih, whh, bih, bhh, wa1, wa2, ifc, ofc, out, ws);
}

// Round 14
// 419.110 us; speedup vs baseline: 2.5988x; 1.0123x over previous
//
#include <hip/hip_runtime.h>
#include <stdint.h>

// Persistent-kernel LSTM NAS controller rollout — tagged dataflow + candidate
// speculation (hop C eliminated). FINAL / measured-best configuration (r10:
// 417.8us). r5-r13 established: cross-WG store->observe visibility ~4.4us is
// invariant across 6 mechanisms; per-step chain has exactly 2 mandatory
// full-vector crossings (h->h1 via W_hh, h1->hw2 via W2) + ~2.2us serial
// sampling => ~11us/step structural floor, which this kernel sits on.
// Failed alternatives: redundant hw2 via L2 stream (r11/r12: ~5x slower than
// the RT), early-publish h1c speculation (r13: publish->poll gap < visibility).
// Structure: 64 wgs x 512 thr; one hidden unit per wave; weights register-
// stationary; cell2 speculated over all candidate node indices (cand[ni] read
// is warm: publish->poll gap = hw2 RT + logits ~6us > 4.4us visibility);
// xproj/aproj tables make cell1/cell2 gate math ~20 ALU ops.
// Tags: A=3t+2 (h1, aw1 row t), K=3t+4 (candidates); init h0 tag 1.
// RNG: JAX threefry2x32 partitionable (bit-exact rounds 2-13).

#define KWG    64
#define NTH    512
#define LSTEPS 32
#define DDIM   512
#define NOPS   16
#define NEGC   (-1.0e9f)

// ---------------- threefry2x32 core ----------------
static __device__ __forceinline__ void tf2x32(uint32_t k0, uint32_t k1,
                                              uint32_t c0, uint32_t c1,
                                              uint32_t& o0, uint32_t& o1){
  uint32_t ks2 = k0 ^ k1 ^ 0x1BD11BDAu;
  uint32_t x0 = c0 + k0;
  uint32_t x1 = c1 + k1;
#define TFR(r) { x0 += x1; x1 = (x1 << (r)) | (x1 >> (32 - (r))); x1 ^= x0; }
  TFR(13) TFR(15) TFR(26) TFR(6)
  x0 += k1;  x1 += ks2 + 1u;
  TFR(17) TFR(29) TFR(16) TFR(24)
  x0 += ks2; x1 += k0 + 2u;
  TFR(13) TFR(15) TFR(26) TFR(6)
  x0 += k0;  x1 += k1 + 3u;
  TFR(17) TFR(29) TFR(16) TFR(24)
  x0 += k1;  x1 += ks2 + 4u;
  TFR(13) TFR(15) TFR(26) TFR(6)
  x0 += ks2; x1 += k0 + 5u;
#undef TFR
  o0 = x0; o1 = x1;
}

static __device__ __forceinline__ float gumbel_bits(uint32_t bits){
  float f = __uint_as_float((bits >> 9) | 0x3f800000u) - 1.0f;
  float u = (f == 0.0f) ? 1.1754943508222875e-38f : f;
  return -logf(-logf(u));
}

static __device__ __forceinline__ float sigm(float x){
  return 1.0f / (1.0f + expf(-x));
}

static __device__ __forceinline__ float wredsum(float v){
  #pragma unroll
  for (int m = 32; m; m >>= 1) v += __shfl_xor(v, m, 64);
  return v;
}

// gather 8 elems at stride 64: d = 64k + lane  (global or LDS)
static __device__ __forceinline__ void gl8(const float* __restrict__ p, int lane, float* r){
  #pragma unroll
  for (int k = 0; k < 8; ++k) r[k] = p[(k << 6) + lane];
}

static __device__ __forceinline__ float dot8(const float* w, const float* x){
  float s = 0.f;
  #pragma unroll
  for (int k = 0; k < 8; ++k) s += w[k]*x[k];
  return s;
}

// ---------------- tagged-atomic helpers (relaxed agent, at MALL) ----------
static __device__ __forceinline__ uint64_t tpack(uint32_t tag, float f){
  return ((uint64_t)tag << 32) | (uint64_t)__float_as_uint(f);
}
static __device__ __forceinline__ uint64_t ald64(const uint64_t* p){
  return __hip_atomic_load(p, __ATOMIC_RELAXED, __HIP_MEMORY_SCOPE_AGENT);
}
static __device__ __forceinline__ void ast64(uint64_t* p, uint64_t v){
  __hip_atomic_store(p, v, __ATOMIC_RELAXED, __HIP_MEMORY_SCOPE_AGENT);
}
static __device__ __forceinline__ float poll1(const uint64_t* p, uint32_t tag){
  uint64_t v = ald64(p);
  while ((uint32_t)(v >> 32) != tag){
    __builtin_amdgcn_s_sleep(1);
    v = ald64(p);
  }
  return __uint_as_float((uint32_t)v);
}
// poll 8 cells (d=64k+lane) into registers (aw1 register rows)
static __device__ __forceinline__ void poll8s(const uint64_t* base, int lane,
                                              uint32_t tag, float* r){
  uint64_t v[8];
  for (;;){
    #pragma unroll
    for (int k = 0; k < 8; ++k) v[k] = ald64(base + (k << 6) + lane);
    bool ok = true;
    #pragma unroll
    for (int k = 0; k < 8; ++k) ok &= ((uint32_t)(v[k] >> 32) == tag);
    if (ok) break;
    __builtin_amdgcn_s_sleep(1);
  }
  #pragma unroll
  for (int k = 0; k < 8; ++k) r[k] = __uint_as_float((uint32_t)v[k]);
}

__global__ void __launch_bounds__(NTH, 2)
Controller_60601988547087_kernel(const float* __restrict__ emb,
                                 const float* __restrict__ wih,
                                 const float* __restrict__ whh,
                                 const float* __restrict__ bih,
                                 const float* __restrict__ bhh,
                                 const float* __restrict__ wa1,
                                 const float* __restrict__ wa2,
                                 const float* __restrict__ idxfc,
                                 const float* __restrict__ opfc,
                                 float* __restrict__ out,
                                 uint64_t* __restrict__ ws64)
{
  const int tid  = threadIdx.x;
  const int wg   = blockIdx.x;
  const int wave = tid >> 6;              // 0..7
  const int lane = tid & 63;
  const int unit = (wg << 3) | wave;      // one hidden unit per wave, 512 total

  // workspace (u64 tagged cells)
  uint64_t* bufA64 = ws64;                // h1      [512]      tags 3t+2
  uint64_t* bufB64 = ws64 + 512;          // h0 init [512]      tag 1
  uint64_t* hw2g64 = ws64 + 1024;         // W2.h1   [512]      tags 3t+3
  uint64_t* aw1g64 = ws64 + 1536;         // aw1 rows[32][512], row t tag 3t+2
  uint64_t* cand64 = ws64 + 1536 + 32*512;// h2 candidates [33][512], tags 3t+4

  __shared__ float s_hc[DDIM];            // carry h (selected h2) staging
  __shared__ float s_h1[DDIM];            // h after cell1
  __shared__ float s_hw2[DDIM];           // h1 @ w_attn_2^T
  __shared__ float s_xproj[17 * 32];      // [op][wave][gate] static W_ih·emb[op]
  __shared__ float s_aproj[33 * 33];      // [row][wave*4+g] stride 33 (bank-safe)
  __shared__ float s_opfc[NOPS * DDIM];   // 32 KB op_fc
  __shared__ float s_logits[33];
  __shared__ float s_oplog[16];
  __shared__ int   s_ibc[2];

  // ---- weights register-stationary, gathered at d = 64k+lane ----
  float wihr[4][8], whhr[4][8], a1r[8], a2r[8], fcr[8], bsum[4];
  #pragma unroll
  for (int g = 0; g < 4; ++g){
    gl8(wih + (size_t)((g << 9) + unit) * DDIM, lane, wihr[g]);
    gl8(whh + (size_t)((g << 9) + unit) * DDIM, lane, whhr[g]);
    bsum[g] = bih[(g << 9) + unit] + bhh[(g << 9) + unit];
  }
  gl8(wa1 + (size_t)unit * DDIM, lane, a1r);
  gl8(wa2 + (size_t)unit * DDIM, lane, a2r);
  gl8(idxfc, lane, fcr);

  for (int i = tid; i < NOPS * DDIM; i += NTH) s_opfc[i] = opfc[i];
  if (tid < 33) s_aproj[tid] = 0.0f;      // aproj row 0: anchors[0] = zeros

  // ---- static x-projections: s_xproj[op][wave][g] = (W_ih · emb[op])[unit] ----
  for (int op = 0; op <= NOPS; ++op){
    float xc[8];
    gl8(emb + (size_t)op * DDIM, lane, xc);
    #pragma unroll
    for (int g = 0; g < 4; ++g){
      float xp = wredsum(dot8(wihr[g], xc));
      if (lane == 0) s_xproj[op * 32 + (wave << 2) + g] = xp;
    }
  }
  __syncthreads();

  // per-wave register cache of aw1 rows (row r owned by wave r&7, slot r>>3)
  float row0[8], row1[8], row2[8], row3[8];

  // ---- init: h0 = cell(emb[16],0,0) via xproj; publish bufB tag 1 ----
  float cst;
  {
    const float* xp = s_xproj + 16 * 32 + (wave << 2);
    float gi = sigm(xp[0] + bsum[0]);
    float go = sigm(xp[3] + bsum[3]);
    cst = gi * tanhf(xp[2] + bsum[2]);   // c=0: forget term vanishes exactly
    float h0 = go * tanhf(cst);
    if (lane == 0) ast64(bufB64 + unit, tpack(1u, h0));
  }
  s_hc[tid] = poll1(bufB64 + tid, 1u);   // stage carry h (= h0)
  __syncthreads();

  uint32_t key0 = 0u, key1v = 42u;       // jax.random.key(42) -> (0, 42)
  float ent_sum = 0.f, lp_sum = 0.f;
  int prev_op = NOPS;                    // inp0 = embedding[16]

  for (int t = 0; t < LSTEPS; ++t){
    const uint32_t tagA = 3u*(uint32_t)t + 2u;
    const uint32_t tagB = 3u*(uint32_t)t + 3u;
    const uint32_t tagK = 3u*(uint32_t)t + 4u;   // candidates

    float hc8[8];
    gl8(s_hc, lane, hc8);                // h2^(t-1) (= anchors[t] for t>=1; h0 at t=0)

    // ========== Stage A (critical): cell1 = xproj[prev_op] + W_hh·h ==========
    {
      const float* xp = s_xproj + prev_op * 32 + (wave << 2);
      float p0 = wredsum(dot8(whhr[0], hc8));
      float p1 = wredsum(dot8(whhr[1], hc8));
      float p2 = wredsum(dot8(whhr[2], hc8));
      float p3 = wredsum(dot8(whhr[3], hc8));
      float gi = sigm(xp[0] + p0 + bsum[0]);
      float gf = sigm(xp[1] + p1 + bsum[1]);
      float go = sigm(xp[3] + p3 + bsum[3]);
      cst = gf * cst + gi * tanhf(xp[2] + p2 + bsum[2]);
      float hn = go * tanhf(cst);
      if (lane == 0) ast64(bufA64 + unit, tpack(tagA, hn));
    }
    // ---- hop-A shadow: aw1 row t publish, aproj row t, owner row fetch ----
    {
      float pa = wredsum(dot8(a1r, hc8));              // row t = W1·h2^(t-1)
      if (lane == 0) ast64(aw1g64 + (size_t)t * DDIM + unit, tpack(tagA, pa));
      if (t > 0){                                      // aproj[t] = W_ih·anchors[t]
        #pragma unroll
        for (int g = 0; g < 4; ++g){
          float ap = wredsum(dot8(wihr[g], hc8));
          if (lane == 0) s_aproj[t * 33 + (wave << 2) + g] = ap;
        }
      }
    }
    if (wave == (t & 7)){                              // owner caches row t
      const uint64_t* rb = aw1g64 + (size_t)t * DDIM;
      int slot = t >> 3;
      if      (slot == 0) poll8s(rb, lane, tagA, row0);
      else if (slot == 1) poll8s(rb, lane, tagA, row1);
      else if (slot == 2) poll8s(rb, lane, tagA, row2);
      else                poll8s(rb, lane, tagA, row3);
    }
    s_h1[tid] = poll1(bufA64 + tid, tagA);             // hop A (RT 1)
    __syncthreads();

    // ========== Stage B: publish hw2; ghh + h2 CANDIDATES in hop-B shadow ====
    float h18[8];
    gl8(s_h1, lane, h18);
    {
      float q = wredsum(dot8(a2r, h18));
      if (lane == 0) ast64(hw2g64 + unit, tpack(tagB, q));
    }
    float ghh0 = wredsum(dot8(whhr[0], h18));          // shadow of hop B
    float ghh1 = wredsum(dot8(whhr[1], h18));
    float ghh2 = wredsum(dot8(whhr[2], h18));
    float ghh3 = wredsum(dot8(whhr[3], h18));
    // ---- candidate cell2 for every possible ni: lane i owns candidate i ----
    float cst_cand = 0.f;
    if (lane <= t){
      const float* ag = s_aproj + lane * 33 + (wave << 2);
      float gi = sigm(ag[0] + ghh0 + bsum[0]);
      float gf = sigm(ag[1] + ghh1 + bsum[1]);
      float go = sigm(ag[3] + ghh3 + bsum[3]);
      cst_cand = gf * cst + gi * tanhf(ag[2] + ghh2 + bsum[2]);
      float h2c = go * tanhf(cst_cand);
      ast64(cand64 + (size_t)lane * DDIM + unit, tpack(tagK, h2c));
    }
    s_hw2[tid] = poll1(hw2g64 + tid, tagB);            // hop B (RT 2)
    __syncthreads();

    // ======== Node logits + sampling — EVERY WG, bit-identical ========
    int ni;
    float nlp_s = 0.f, nent_s = 0.f;
    uint32_t k2a_s = 0u, k2b_s = 0u;
    {
      float h2c[8];
      gl8(s_hw2, lane, h2c);
#define ROWDOT(RR, I)                                                          \
      { int i_ = (I);                                                          \
        if (i_ <= t){                                                          \
          float acc = 0.f;                                                     \
          _Pragma("unroll")                                                    \
          for (int k = 0; k < 8; ++k) acc += tanhf(RR[k] + h2c[k]) * fcr[k];   \
          acc = wredsum(acc);                                                  \
          if (lane == 0) s_logits[i_] = 2.5f * tanhf(acc / 5.0f);              \
        } }
      ROWDOT(row0, wave)
      ROWDOT(row1, wave + 8)
      ROWDOT(row2, wave + 16)
      ROWDOT(row3, wave + 24)
#undef ROWDOT
      __syncthreads();
      if (wave == 0){
        // split(key,3), partitionable/foldlike: row i = tf(key, (0, i))
        uint32_t s0 = 0, s1 = 0;
        if (lane < 3) tf2x32(key0, key1v, 0u, (uint32_t)lane, s0, s1);
        uint32_t k1a = __shfl(s0, 0, 64), k1b = __shfl(s1, 0, 64);
        k2a_s = __shfl(s0, 1, 64); k2b_s = __shfl(s1, 1, 64);
        uint32_t nk0 = __shfl(s0, 2, 64), nk1 = __shfl(s1, 2, 64);
        key0 = nk0; key1v = nk1;
        // 33 random bits: bits[i] = x0 ^ x1 of tf(k1, (0, i))
        uint32_t y0 = 0, y1 = 0;
        if (lane < 33) tf2x32(k1a, k1b, 0u, (uint32_t)lane, y0, y1);
        uint32_t bits = y0 ^ y1;
        float gmb   = gumbel_bits(bits);
        float logit = (lane < 33) ? ((lane <= t) ? s_logits[lane] : NEGC) : -3.0e38f;
        float cand  = (lane < 33) ? (logit + gmb) : -3.0e38f;
        float v = cand; int bi = lane;
        #pragma unroll
        for (int m = 32; m; m >>= 1){
          float ov = __shfl_xor(v, m, 64); int ob = __shfl_xor(bi, m, 64);
          if (ov > v || (ov == v && ob < bi)){ v = ov; bi = ob; }
        }
        int ni_ = bi;
        float lm = (lane < 33) ? logit : -3.0e38f;
        #pragma unroll
        for (int m = 32; m; m >>= 1) lm = fmaxf(lm, __shfl_xor(lm, m, 64));
        float ex   = (lane < 33) ? expf(logit - lm) : 0.f;
        float ssum = wredsum(ex);
        float lsm  = logit - lm - logf(ssum);
        nlp_s  = -__shfl(lsm, ni_, 64);
        float entc = (lane <= t) ? (-lsm * expf(lsm)) : 0.f;
        nent_s = wredsum(entc);
        if (lane == 0) s_ibc[0] = ni_;
      }
      __syncthreads();
      ni = s_ibc[0];
    }

    // ========== Select h2 = cand[ni] (published ~6us ago -> warm) ==========
    cst = __shfl(cst_cand, ni, 64);                    // own unit's cst
    s_hc[tid] = poll1(cand64 + (size_t)ni * DDIM + tid, tagK);
    __syncthreads();

    // ========== Tail (local): op logits + sample -> prev_op ==========
    {
      float h28[8];
      gl8(s_hc, lane, h28);
      #pragma unroll
      for (int jj = 0; jj < 2; ++jj){
        int i = wave + (jj << 3);
        float acc = 0.f;
        #pragma unroll
        for (int k = 0; k < 8; ++k) acc += s_opfc[i * DDIM + (k << 6) + lane] * h28[k];
        acc = wredsum(acc);
        if (lane == 0) s_oplog[i] = tanhf(acc / 5.0f);  // (2.5/2.5)=1 scale
      }
      __syncthreads();
    }
    int oi;
    {
      if (wave == 0){
        // 16 random bits: bits[i] = x0 ^ x1 of tf(k2, (0, i))
        uint32_t z0 = 0, z1 = 0;
        if (lane < 16) tf2x32(k2a_s, k2b_s, 0u, (uint32_t)lane, z0, z1);
        uint32_t bits = z0 ^ z1;
        float gmb   = gumbel_bits(bits);
        float logit = (lane < 16) ? s_oplog[lane] : -3.0e38f;
        float cand  = (lane < 16) ? (logit + gmb) : -3.0e38f;
        float v = cand; int bi = lane;
        #pragma unroll
        for (int m = 32; m; m >>= 1){
          float ov = __shfl_xor(v, m, 64); int ob = __shfl_xor(bi, m, 64);
          if (ov > v || (ov == v && ob < bi)){ v = ov; bi = ob; }
        }
        int oi_ = bi;
        float lm = (lane < 16) ? logit : -3.0e38f;
        #pragma unroll
        for (int m = 32; m; m >>= 1) lm = fmaxf(lm, __shfl_xor(lm, m, 64));
        float ex   = (lane < 16) ? expf(logit - lm) : 0.f;
        float ssum = wredsum(ex);
        float olsm = logit - lm - logf(ssum);
        float olp  = -__shfl(olsm, oi_, 64);
        float oent = wredsum((lane < 16) ? (-olsm * expf(olsm)) : 0.f);
        lp_sum  += nlp_s + olp;
        ent_sum += nent_s + oent;
        if (lane == 0){
          s_ibc[1] = oi_;
          if (wg == 0){
            out[2 * t]     = (float)ni;
            out[2 * t + 1] = (float)oi_;
          }
        }
      }
      __syncthreads();
      oi = s_ibc[1];
    }
    prev_op = oi;
  }

  if (wg == 0 && wave == 0 && lane == 0){
    out[64] = ent_sum;
    out[65] = lp_sum;
  }
}

extern "C" void kernel_launch(void* const* d_in, const int* in_sizes, int n_in,
                              void* d_out, int out_size, void* d_ws, size_t ws_size,
                              hipStream_t stream) {
  (void)in_sizes; (void)n_in; (void)out_size; (void)ws_size;
  const float* emb  = (const float*)d_in[0];
  const float* wih  = (const float*)d_in[1];
  const float* whh  = (const float*)d_in[2];
  const float* bih  = (const float*)d_in[3];
  const float* bhh  = (const float*)d_in[4];
  const float* wa1  = (const float*)d_in[5];
  const float* wa2  = (const float*)d_in[6];
  const float* ifc  = (const float*)d_in[7];
  const float* ofc  = (const float*)d_in[8];
  float* out = (float*)d_out;
  uint64_t* ws = (uint64_t*)d_ws;
  hipLaunchKernelGGL(Controller_60601988547087_kernel,
                     dim3(KWG), dim3(NTH), 0, stream,
                     emb, wih, whh, bih, bhh, wa1, wa2, ifc, ofc, out, ws);
}